// Round 9
// baseline (413.200 us; speedup 1.0000x reference)
//
#include <hip/hip_runtime.h>
#include <stdint.h>

#define BATCH 64
#define SLEN 512
#define HID 128
#define NHEAD 4
#define DPROJ 512            // HID * NHEAD
#define MTOT (BATCH * SLEN)  // 32768
#define SCALE 0.08838834764831845f
#define LOG2E 1.4426950408889634f

using short8 = __attribute__((ext_vector_type(8))) short;
using f32x4  = __attribute__((ext_vector_type(4))) float;
using u32x4  = __attribute__((ext_vector_type(4))) unsigned int;
using u32x2  = __attribute__((ext_vector_type(2))) unsigned int;
using us4    = __attribute__((ext_vector_type(4))) unsigned short;

__device__ __forceinline__ unsigned short f2bf(float f) {
  unsigned int u = __float_as_uint(f);
  u += 0x7fffu + ((u >> 16) & 1u);   // round-to-nearest-even
  return (unsigned short)(u >> 16);
}

// ---------------------------------------------------------------------------
// Kernel 0: prep. blocks 0..1023: weight cast+transpose (Wq pre-scaled by
// SCALE*log2(e) so attn uses exp2). blocks 1024..3071: enc fp32->bf16.
// blocks 3072..19455: mask -> bitmask.
// ---------------------------------------------------------------------------
__global__ __launch_bounds__(256) void prep_kernel(
    const float* __restrict__ Wq,
    const float* __restrict__ Wk,
    const float* __restrict__ Wv,
    const float* __restrict__ Wo,
    const float* __restrict__ enc,
    const int* __restrict__ mask,
    unsigned short* __restrict__ WT,
    unsigned short* __restrict__ WoT,
    unsigned short* __restrict__ encb,
    unsigned int* __restrict__ mbits)
{
  if (blockIdx.x < 1024) {
    int idx = blockIdx.x * 256 + threadIdx.x;
    int z = idx >> 16;
    int i = idx & 65535;
    if (z < 3) {
      const float* W = (z == 0) ? Wq : (z == 1) ? Wk : Wv;
      float scale = (z == 0) ? (SCALE * LOG2E) : 1.0f;  // exp2 form
      int k = i >> 9;
      int n = i & 511;
      WT[(size_t)z * 65536 + (size_t)n * 128 + k] = f2bf(W[i] * scale);
    } else {
      int k = i >> 7;
      int n = i & 127;
      WoT[(size_t)n * 512 + k] = f2bf(Wo[i]);
    }
  } else if (blockIdx.x < 3072) {
    size_t tid = (size_t)(blockIdx.x - 1024) * 256 + threadIdx.x;  // 0..524287
    const float* s = enc + tid * 8;
    f32x4 a0 = *(const f32x4*)(s);
    f32x4 a1 = *(const f32x4*)(s + 4);
    short8 v;
    #pragma unroll
    for (int j = 0; j < 4; ++j) v[j] = (short)f2bf(a0[j]);
    #pragma unroll
    for (int j = 0; j < 4; ++j) v[4 + j] = (short)f2bf(a1[j]);
    *(short8*)(encb + tid * 8) = v;
  } else {
    const int l = threadIdx.x & 63;
    size_t wavebase = (size_t)(blockIdx.x - 3072) * 1024 + (threadIdx.x >> 6) * 256;
    unsigned long long b0 = __ballot(mask[wavebase + 0 * 64 + l] != 0);
    unsigned long long b1 = __ballot(mask[wavebase + 1 * 64 + l] != 0);
    unsigned long long b2 = __ballot(mask[wavebase + 2 * 64 + l] != 0);
    unsigned long long b3 = __ballot(mask[wavebase + 3 * 64 + l] != 0);
    if (l < 4) {
      unsigned long long v = (l & 2) ? ((l & 1) ? b3 : b2) : ((l & 1) ? b1 : b0);
      *(unsigned long long*)(mbits + (wavebase >> 5) + l * 2) = v;
    }
  }
}

// ---------------------------------------------------------------------------
// Kernel 1: QKV projection (unchanged from R8). Grid (4 heads, 256 mt);
// z-loop inside; A-tile staged once, reused 3x; full K=128 in LDS.
// Q/K: swapped-operand MFMA (reg axis = d) -> packed us4 stores.
// V: written transposed (reg axis = s).
// ---------------------------------------------------------------------------
__global__ __launch_bounds__(256) void qkv_kernel(
    const unsigned short* __restrict__ encb,  // (M,128) bf16
    const unsigned short* __restrict__ WT,    // (3,512,128) bf16 n-major
    unsigned short* __restrict__ Qh,
    unsigned short* __restrict__ Kh,
    unsigned short* __restrict__ Vt)
{
  const int nt = blockIdx.x;   // 0..3 == head
  const int mt = blockIdx.y;   // 0..255
  const int t = threadIdx.x;
  const int lane = t & 63;
  const int w = t >> 6;
  const int quad = lane >> 4;
  const int l16 = lane & 15;

  __shared__ __align__(16) unsigned short Ald[128 * 136];  // enc rows x K=128
  __shared__ __align__(16) unsigned short Bld[128 * 136];  // W rows (n) x K

  const int m0 = mt * 128, n0 = nt * 128;
  const int wm = (w >> 1) * 64, wn = (w & 1) * 64;

  #pragma unroll
  for (int i = 0; i < 8; ++i) {
    int idx = i * 256 + t;
    int row = idx >> 4;
    int col = (idx & 15) << 3;
    *(u32x4*)(Ald + row * 136 + col) =
        *(const u32x4*)(encb + (size_t)(m0 + row) * HID + col);
  }

  for (int z = 0; z < 3; ++z) {
    __syncthreads();
    const unsigned short* Wz = WT + (size_t)z * DPROJ * HID;
    #pragma unroll
    for (int i = 0; i < 8; ++i) {
      int idx = i * 256 + t;
      int row = idx >> 4;
      int col = (idx & 15) << 3;
      *(u32x4*)(Bld + row * 136 + col) =
          *(const u32x4*)(Wz + (size_t)(n0 + row) * HID + col);
    }
    __syncthreads();

    f32x4 acc[4][4];
    #pragma unroll
    for (int mi = 0; mi < 4; ++mi)
      #pragma unroll
      for (int ni = 0; ni < 4; ++ni)
        acc[mi][ni] = f32x4{0.f, 0.f, 0.f, 0.f};

    #pragma unroll
    for (int kk = 0; kk < 4; ++kk) {
      short8 a[4], bb[4];
      #pragma unroll
      for (int mi = 0; mi < 4; ++mi)
        a[mi] = *(const short8*)(Ald + (wm + mi * 16 + l16) * 136 + kk * 32 + quad * 8);
      #pragma unroll
      for (int ni = 0; ni < 4; ++ni)
        bb[ni] = *(const short8*)(Bld + (wn + ni * 16 + l16) * 136 + kk * 32 + quad * 8);
      if (z < 2) {
        #pragma unroll
        for (int mi = 0; mi < 4; ++mi)
          #pragma unroll
          for (int ni = 0; ni < 4; ++ni)
            acc[mi][ni] = __builtin_amdgcn_mfma_f32_16x16x32_bf16(bb[ni], a[mi], acc[mi][ni], 0, 0, 0);
      } else {
        #pragma unroll
        for (int mi = 0; mi < 4; ++mi)
          #pragma unroll
          for (int ni = 0; ni < 4; ++ni)
            acc[mi][ni] = __builtin_amdgcn_mfma_f32_16x16x32_bf16(a[mi], bb[ni], acc[mi][ni], 0, 0, 0);
      }
    }

    if (z < 2) {
      unsigned short* outz = ((z == 0) ? Qh : Kh) + (size_t)nt * MTOT * HID;
      #pragma unroll
      for (int mi = 0; mi < 4; ++mi)
        #pragma unroll
        for (int ni = 0; ni < 4; ++ni) {
          int m = m0 + wm + mi * 16 + l16;
          int dbase = wn + ni * 16 + quad * 4;
          us4 pk;
          #pragma unroll
          for (int r = 0; r < 4; ++r) pk[r] = f2bf(acc[mi][ni][r]);
          *(us4*)(outz + (size_t)m * HID + dbase) = pk;
        }
    } else {
      #pragma unroll
      for (int mi = 0; mi < 4; ++mi)
        #pragma unroll
        for (int ni = 0; ni < 4; ++ni) {
          int row0 = m0 + wm + mi * 16 + quad * 4;
          int b = row0 >> 9, s = row0 & 511;
          int d = wn + ni * 16 + l16;
          us4 pk;
          #pragma unroll
          for (int r = 0; r < 4; ++r) pk[r] = f2bf(acc[mi][ni][r]);
          *(us4*)(Vt + ((size_t)(nt * BATCH + b) * HID + d) * SLEN + s) = pk;
        }
    }
  }
}

// ---------------------------------------------------------------------------
// Kernel 2: flash attention — ZERO LDS, ZERO barriers. 64-q tile, 256 thr,
// 2048 blocks XCD-swizzled (all 8 q-tiles of an (h,b) on one XCD).
// K and V fragments load directly from global: per instruction 16 rows x one
// 64B line (L1-resident per chunk: K 16KB + V 16KB). QK uses swapped operands
// (D[key][q]) so P lands with 4 consecutive keys per lane; the A-fragment for
// PV is built in-register via 64-bit shuffles (no LDS round trip, no fence).
// Mask: one u64 per lane per chunk. exp2 (log2e folded into Wq).
// launch_bounds (256,4): VGPR cap 128 — R7 showed tighter caps spill.
// ---------------------------------------------------------------------------
__global__ __launch_bounds__(256, 4) void attn_kernel(
    const unsigned short* __restrict__ Qh,   // (NH, M, 128)
    const unsigned short* __restrict__ Kh,   // (NH, M, 128)
    const unsigned short* __restrict__ Vt,   // (NH, B, 128, S)
    const unsigned int* __restrict__ mbits,  // (B, S, 16)
    unsigned short* __restrict__ ctx)        // (M, 512)
{
  const int lin = blockIdx.x;              // 0..2047
  const int work = (lin & 7) * 256 + (lin >> 3);
  const int qt = work & 7;                 // 0..7
  const int hb = work >> 3;                // 0..255
  const int h = hb & 3, b = hb >> 2;

  const int t = threadIdx.x;
  const int lane = t & 63;
  const int w = t >> 6;                    // 0..3
  const int quad = lane >> 4;
  const int l16 = lane & 15;

  const int q0 = qt * 64;
  const size_t rowbase = (size_t)b * SLEN;
  const unsigned short* kbase = Kh + ((size_t)h * MTOT + rowbase) * HID;
  const unsigned short* vbase = Vt + (size_t)(h * BATCH + b) * HID * SLEN;
  // this lane's q row (for QK result columns and mask)
  const int qrow = q0 + w * 16 + l16;
  const unsigned int* mrow = mbits + ((size_t)b * SLEN + qrow) * 16;

  // Q fragments (B-operand): rows q0 + w*16 + l16
  short8 qa[4];
  {
    const unsigned short* qbase =
        Qh + ((size_t)h * MTOT + rowbase + qrow) * HID + quad * 8;
    #pragma unroll
    for (int kk = 0; kk < 4; ++kk)
      qa[kk] = *(const short8*)(qbase + kk * 32);
  }

  short8 ones;
  #pragma unroll
  for (int j = 0; j < 8; ++j) ones[j] = (short)0x3F80;  // bf16 1.0

  f32x4 oc[8], oc9;
  #pragma unroll
  for (int nd = 0; nd < 8; ++nd) oc[nd] = f32x4{0.f, 0.f, 0.f, 0.f};
  oc9 = f32x4{0.f, 0.f, 0.f, 0.f};

  const int srcA = 2 * (quad & 1) * 16 + l16;   // shuffle source lane (lo half)

  for (int c0 = 0; c0 < SLEN; c0 += 64) {
    // S^T = K Q^T : sc[ni] rows = keys c0+ni*16+quad*4+r, cols = q (l16)
    f32x4 sc[4];
    #pragma unroll
    for (int ni = 0; ni < 4; ++ni) sc[ni] = f32x4{0.f, 0.f, 0.f, 0.f};
    #pragma unroll
    for (int kk = 0; kk < 4; ++kk) {
      #pragma unroll
      for (int ni = 0; ni < 4; ++ni) {
        short8 bb = *(const short8*)(kbase + (size_t)(c0 + ni * 16 + l16) * HID + kk * 32 + quad * 8);
        sc[ni] = __builtin_amdgcn_mfma_f32_16x16x32_bf16(bb, qa[kk], sc[ni], 0, 0, 0);
      }
    }

    // mask bits for this lane's q, keys c0..c0+63
    u32x2 mw = *(const u32x2*)(mrow + (c0 >> 5));
    unsigned long long mk = ((unsigned long long)mw[1] << 32) | (unsigned long long)mw[0];

    // p = mask ? exp2(s) : 0, packed bf16 x4 (keys quad*4+r consecutive)
    unsigned long long pk64[4];
    #pragma unroll
    for (int ni = 0; ni < 4; ++ni) {
      us4 pk;
      #pragma unroll
      for (int r = 0; r < 4; ++r) {
        float e = exp2f(sc[ni][r]);
        float p = ((mk >> (ni * 16 + quad * 4 + r)) & 1ull) ? e : 0.f;
        pk[r] = f2bf(p);
      }
      pk64[ni] = *(unsigned long long*)&pk;
    }

    // build P A-frags via in-register shuffles; O += P @ V ; rowsum += P @ 1
    #pragma unroll
    for (int kb = 0; kb < 2; ++kb) {
      unsigned long long lo0 = __shfl(pk64[2 * kb + 0], srcA, 64);
      unsigned long long lo1 = __shfl(pk64[2 * kb + 1], srcA, 64);
      unsigned long long hi0 = __shfl(pk64[2 * kb + 0], srcA + 16, 64);
      unsigned long long hi1 = __shfl(pk64[2 * kb + 1], srcA + 16, 64);
      unsigned long long lo = (quad & 2) ? lo1 : lo0;
      unsigned long long hi = (quad & 2) ? hi1 : hi0;
      union { struct { unsigned long long x, y; } u; short8 v; } af;
      af.u.x = lo; af.u.y = hi;
      short8 a = af.v;   // P[q=l16][keys c0+kb*32+quad*8 .. +7]
      #pragma unroll
      for (int nd = 0; nd < 8; ++nd) {
        short8 bv = *(const short8*)(vbase + (size_t)(nd * 16 + l16) * SLEN + c0 + kb * 32 + quad * 8);
        oc[nd] = __builtin_amdgcn_mfma_f32_16x16x32_bf16(a, bv, oc[nd], 0, 0, 0);
      }
      oc9 = __builtin_amdgcn_mfma_f32_16x16x32_bf16(a, ones, oc9, 0, 0, 0);
    }
  }

  // D[q][d]: row quad*4+r -> q, col l16 -> d (R6-style write-combining stores)
  #pragma unroll
  for (int r = 0; r < 4; ++r) {
    float rcp = 1.0f / oc9[r];
    int row = q0 + w * 16 + quad * 4 + r;
    unsigned short* crow = ctx + (rowbase + row) * DPROJ + h * HID;
    #pragma unroll
    for (int nd = 0; nd < 8; ++nd)
      crow[nd * 16 + l16] = f2bf(oc[nd][r] * rcp);
  }
}

// ---------------------------------------------------------------------------
// Kernel 3: fused output projection + residual + LayerNorm (unchanged R8).
// ---------------------------------------------------------------------------
__global__ __launch_bounds__(256, 4) void oproj_ln_kernel(
    const unsigned short* __restrict__ ctx,   // (M,512) bf16
    const unsigned short* __restrict__ WoT,   // (128,512) bf16 n-major
    const float* __restrict__ enc,            // (M,128) fp32
    const float* __restrict__ gamma,
    const float* __restrict__ beta,
    float* __restrict__ out)                  // (M,128) fp32
{
  const int m0 = blockIdx.x * 64;
  const int t = threadIdx.x;
  const int lane = t & 63;
  const int w = t >> 6;
  const int quad = lane >> 4;
  const int l16 = lane & 15;

  __shared__ __align__(16) unsigned short Actx[64 * 72];
  __shared__ __align__(16) unsigned short Bw[128 * 72];

  f32x4 acc[8];
  #pragma unroll
  for (int ni = 0; ni < 8; ++ni) acc[ni] = f32x4{0.f, 0.f, 0.f, 0.f};

  for (int kc = 0; kc < DPROJ; kc += 64) {
    __syncthreads();
    #pragma unroll
    for (int i = 0; i < 2; ++i) {
      int idx = i * 256 + t;
      int row = idx >> 3;
      int col = (idx & 7) << 3;
      *(u32x4*)(Actx + row * 72 + col) =
          *(const u32x4*)(ctx + (size_t)(m0 + row) * DPROJ + kc + col);
    }
    #pragma unroll
    for (int i = 0; i < 4; ++i) {
      int idx = i * 256 + t;
      int row = idx >> 3;
      int col = (idx & 7) << 3;
      *(u32x4*)(Bw + row * 72 + col) =
          *(const u32x4*)(WoT + (size_t)row * DPROJ + kc + col);
    }
    __syncthreads();
    #pragma unroll
    for (int kk = 0; kk < 2; ++kk) {
      short8 a = *(const short8*)(Actx + (w * 16 + l16) * 72 + kk * 32 + quad * 8);
      #pragma unroll
      for (int ni = 0; ni < 8; ++ni) {
        short8 bb = *(const short8*)(Bw + (ni * 16 + l16) * 72 + kk * 32 + quad * 8);
        acc[ni] = __builtin_amdgcn_mfma_f32_16x16x32_bf16(a, bb, acc[ni], 0, 0, 0);
      }
    }
  }

  float g[8], be[8];
  #pragma unroll
  for (int ni = 0; ni < 8; ++ni) {
    g[ni] = gamma[ni * 16 + l16];
    be[ni] = beta[ni * 16 + l16];
  }

  float val[8][4];
  #pragma unroll
  for (int r = 0; r < 4; ++r) {
    int m = m0 + w * 16 + quad * 4 + r;
    const float* erow = enc + (size_t)m * HID;
    float s = 0.f, s2 = 0.f;
    #pragma unroll
    for (int ni = 0; ni < 8; ++ni) {
      float v = acc[ni][r] + erow[ni * 16 + l16];
      val[ni][r] = v;
      s += v;
      s2 += v * v;
    }
    #pragma unroll
    for (int off = 1; off < 16; off <<= 1) {
      s  += __shfl_xor(s, off, 64);
      s2 += __shfl_xor(s2, off, 64);
    }
    float mean = s * (1.f / 128.f);
    float var = s2 * (1.f / 128.f) - mean * mean;
    float rstd = rsqrtf(var + 1e-6f);
    float* orow = out + (size_t)m * HID;
    #pragma unroll
    for (int ni = 0; ni < 8; ++ni)
      orow[ni * 16 + l16] = g[ni] * (val[ni][r] - mean) * rstd + be[ni];
  }
}

// ---------------------------------------------------------------------------
// ws layout (elements):
//   WT   : 3*512*128 shorts        WoT : 128*512 shorts
//   Qh   : 4*M*128 shorts          Kh  : 4*M*128 shorts
//   Vt   : 4*64*128*512 shorts     ctx : M*512 shorts
//   encb : M*128 shorts (fp32-sized slot)
//   mbits: 64*512*16 u32           (~153.6 MB total)
// ---------------------------------------------------------------------------
extern "C" void kernel_launch(void* const* d_in, const int* in_sizes, int n_in,
                              void* d_out, int out_size, void* d_ws, size_t ws_size,
                              hipStream_t stream) {
  const float* enc   = (const float*)d_in[0];
  const int*   mask  = (const int*)d_in[1];
  const float* Wq    = (const float*)d_in[2];
  const float* Wk    = (const float*)d_in[3];
  const float* Wv    = (const float*)d_in[4];
  const float* Wo    = (const float*)d_in[5];
  const float* gamma = (const float*)d_in[6];
  const float* beta  = (const float*)d_in[7];
  float* out = (float*)d_out;

  unsigned short* WT  = (unsigned short*)d_ws;
  unsigned short* WoT = WT + (size_t)3 * DPROJ * HID;
  unsigned short* Qh  = WoT + (size_t)HID * DPROJ;
  unsigned short* Kh  = Qh + (size_t)NHEAD * MTOT * HID;
  unsigned short* Vt  = Kh + (size_t)NHEAD * MTOT * HID;
  unsigned short* ctx = Vt + (size_t)NHEAD * MTOT * HID;
  unsigned short* encb = ctx + (size_t)MTOT * DPROJ;
  unsigned int* mbits = (unsigned int*)(encb + (size_t)MTOT * HID * 2);

  prep_kernel<<<19456, 256, 0, stream>>>(Wq, Wk, Wv, Wo, enc, mask, WT, WoT, encb, mbits);
  qkv_kernel<<<dim3(4, 256), 256, 0, stream>>>(encb, WT, Qh, Kh, Vt);
  attn_kernel<<<2048, 256, 0, stream>>>(Qh, Kh, Vt, mbits, ctx);
  oproj_ln_kernel<<<MTOT / 64, 256, 0, stream>>>(ctx, WoT, enc, gamma, beta, out);
}

// Round 10
// 242.396 us; speedup vs baseline: 1.7046x; 1.7046x over previous
//
#include <hip/hip_runtime.h>
#include <stdint.h>

#define BATCH 64
#define SLEN 512
#define HID 128
#define NHEAD 4
#define DPROJ 512            // HID * NHEAD
#define MTOT (BATCH * SLEN)  // 32768
#define SCALE 0.08838834764831845f
#define LOG2E 1.4426950408889634f

using short8 = __attribute__((ext_vector_type(8))) short;
using f32x4  = __attribute__((ext_vector_type(4))) float;
using u32x4  = __attribute__((ext_vector_type(4))) unsigned int;
using u32x2  = __attribute__((ext_vector_type(2))) unsigned int;
using us4    = __attribute__((ext_vector_type(4))) unsigned short;

__device__ __forceinline__ unsigned short f2bf(float f) {
  unsigned int u = __float_as_uint(f);
  u += 0x7fffu + ((u >> 16) & 1u);   // round-to-nearest-even
  return (unsigned short)(u >> 16);
}

// ---------------------------------------------------------------------------
// Kernel 0: prep. blocks 0..1023: weight cast+transpose (Wq pre-scaled by
// SCALE*log2(e) so attn uses exp2). blocks 1024..3071: enc fp32->bf16.
// blocks 3072..19455: mask -> bitmask.
// ---------------------------------------------------------------------------
__global__ __launch_bounds__(256) void prep_kernel(
    const float* __restrict__ Wq,
    const float* __restrict__ Wk,
    const float* __restrict__ Wv,
    const float* __restrict__ Wo,
    const float* __restrict__ enc,
    const int* __restrict__ mask,
    unsigned short* __restrict__ WT,
    unsigned short* __restrict__ WoT,
    unsigned short* __restrict__ encb,
    unsigned int* __restrict__ mbits)
{
  if (blockIdx.x < 1024) {
    int idx = blockIdx.x * 256 + threadIdx.x;
    int z = idx >> 16;
    int i = idx & 65535;
    if (z < 3) {
      const float* W = (z == 0) ? Wq : (z == 1) ? Wk : Wv;
      float scale = (z == 0) ? (SCALE * LOG2E) : 1.0f;  // exp2 form
      int k = i >> 9;
      int n = i & 511;
      WT[(size_t)z * 65536 + (size_t)n * 128 + k] = f2bf(W[i] * scale);
    } else {
      int k = i >> 7;
      int n = i & 127;
      WoT[(size_t)n * 512 + k] = f2bf(Wo[i]);
    }
  } else if (blockIdx.x < 3072) {
    size_t tid = (size_t)(blockIdx.x - 1024) * 256 + threadIdx.x;  // 0..524287
    const float* s = enc + tid * 8;
    f32x4 a0 = *(const f32x4*)(s);
    f32x4 a1 = *(const f32x4*)(s + 4);
    short8 v;
    #pragma unroll
    for (int j = 0; j < 4; ++j) v[j] = (short)f2bf(a0[j]);
    #pragma unroll
    for (int j = 0; j < 4; ++j) v[4 + j] = (short)f2bf(a1[j]);
    *(short8*)(encb + tid * 8) = v;
  } else {
    const int l = threadIdx.x & 63;
    size_t wavebase = (size_t)(blockIdx.x - 3072) * 1024 + (threadIdx.x >> 6) * 256;
    unsigned long long b0 = __ballot(mask[wavebase + 0 * 64 + l] != 0);
    unsigned long long b1 = __ballot(mask[wavebase + 1 * 64 + l] != 0);
    unsigned long long b2 = __ballot(mask[wavebase + 2 * 64 + l] != 0);
    unsigned long long b3 = __ballot(mask[wavebase + 3 * 64 + l] != 0);
    if (l < 4) {
      unsigned long long v = (l & 2) ? ((l & 1) ? b3 : b2) : ((l & 1) ? b1 : b0);
      *(unsigned long long*)(mbits + (wavebase >> 5) + l * 2) = v;
    }
  }
}

// ---------------------------------------------------------------------------
// Kernel 1: QKV projection (R8 version, measured good). Grid (4 heads,
// 256 mt); z-loop inside; A-tile staged once, reused 3x; full K=128 in LDS.
// Q/K: swapped-operand MFMA (reg axis = d) -> packed us4 stores.
// V: written transposed (reg axis = s).
// ---------------------------------------------------------------------------
__global__ __launch_bounds__(256) void qkv_kernel(
    const unsigned short* __restrict__ encb,  // (M,128) bf16
    const unsigned short* __restrict__ WT,    // (3,512,128) bf16 n-major
    unsigned short* __restrict__ Qh,
    unsigned short* __restrict__ Kh,
    unsigned short* __restrict__ Vt)
{
  const int nt = blockIdx.x;   // 0..3 == head
  const int mt = blockIdx.y;   // 0..255
  const int t = threadIdx.x;
  const int lane = t & 63;
  const int w = t >> 6;
  const int quad = lane >> 4;
  const int l16 = lane & 15;

  __shared__ __align__(16) unsigned short Ald[128 * 136];  // enc rows x K=128
  __shared__ __align__(16) unsigned short Bld[128 * 136];  // W rows (n) x K

  const int m0 = mt * 128, n0 = nt * 128;
  const int wm = (w >> 1) * 64, wn = (w & 1) * 64;

  #pragma unroll
  for (int i = 0; i < 8; ++i) {
    int idx = i * 256 + t;
    int row = idx >> 4;
    int col = (idx & 15) << 3;
    *(u32x4*)(Ald + row * 136 + col) =
        *(const u32x4*)(encb + (size_t)(m0 + row) * HID + col);
  }

  for (int z = 0; z < 3; ++z) {
    __syncthreads();
    const unsigned short* Wz = WT + (size_t)z * DPROJ * HID;
    #pragma unroll
    for (int i = 0; i < 8; ++i) {
      int idx = i * 256 + t;
      int row = idx >> 4;
      int col = (idx & 15) << 3;
      *(u32x4*)(Bld + row * 136 + col) =
          *(const u32x4*)(Wz + (size_t)(n0 + row) * HID + col);
    }
    __syncthreads();

    f32x4 acc[4][4];
    #pragma unroll
    for (int mi = 0; mi < 4; ++mi)
      #pragma unroll
      for (int ni = 0; ni < 4; ++ni)
        acc[mi][ni] = f32x4{0.f, 0.f, 0.f, 0.f};

    #pragma unroll
    for (int kk = 0; kk < 4; ++kk) {
      short8 a[4], bb[4];
      #pragma unroll
      for (int mi = 0; mi < 4; ++mi)
        a[mi] = *(const short8*)(Ald + (wm + mi * 16 + l16) * 136 + kk * 32 + quad * 8);
      #pragma unroll
      for (int ni = 0; ni < 4; ++ni)
        bb[ni] = *(const short8*)(Bld + (wn + ni * 16 + l16) * 136 + kk * 32 + quad * 8);
      if (z < 2) {
        #pragma unroll
        for (int mi = 0; mi < 4; ++mi)
          #pragma unroll
          for (int ni = 0; ni < 4; ++ni)
            acc[mi][ni] = __builtin_amdgcn_mfma_f32_16x16x32_bf16(bb[ni], a[mi], acc[mi][ni], 0, 0, 0);
      } else {
        #pragma unroll
        for (int mi = 0; mi < 4; ++mi)
          #pragma unroll
          for (int ni = 0; ni < 4; ++ni)
            acc[mi][ni] = __builtin_amdgcn_mfma_f32_16x16x32_bf16(a[mi], bb[ni], acc[mi][ni], 0, 0, 0);
      }
    }

    if (z < 2) {
      unsigned short* outz = ((z == 0) ? Qh : Kh) + (size_t)nt * MTOT * HID;
      #pragma unroll
      for (int mi = 0; mi < 4; ++mi)
        #pragma unroll
        for (int ni = 0; ni < 4; ++ni) {
          int m = m0 + wm + mi * 16 + l16;
          int dbase = wn + ni * 16 + quad * 4;
          us4 pk;
          #pragma unroll
          for (int r = 0; r < 4; ++r) pk[r] = f2bf(acc[mi][ni][r]);
          *(us4*)(outz + (size_t)m * HID + dbase) = pk;
        }
    } else {
      #pragma unroll
      for (int mi = 0; mi < 4; ++mi)
        #pragma unroll
        for (int ni = 0; ni < 4; ++ni) {
          int row0 = m0 + wm + mi * 16 + quad * 4;
          int b = row0 >> 9, s = row0 & 511;
          int d = wn + ni * 16 + l16;
          us4 pk;
          #pragma unroll
          for (int r = 0; r < 4; ++r) pk[r] = f2bf(acc[mi][ni][r]);
          *(us4*)(Vt + ((size_t)(nt * BATCH + b) * HID + d) * SLEN + s) = pk;
        }
    }
  }
}

// ---------------------------------------------------------------------------
// Kernel 2: flash attention — R6 version restored verbatim (measured 67.4 µs;
// best of R6/R7/R8/R9). 128-q tile, 512 thr, XCD swizzle, K/V register
// prefetch into LDS (the staging IS the latency-hiding: R9's LDS-free variant
// was 3.7x slower at identical traffic). Pld padded 128x72 + fence.
// Only change vs R6: exp2f (LOG2E folded into Wq by prep).
// launch_bounds (512,4): (512,6) caps VGPR at 85 -> spills (R7).
// ---------------------------------------------------------------------------
__global__ __launch_bounds__(512, 4) void attn_kernel(
    const unsigned short* __restrict__ Qh,   // (NH, M, 128)
    const unsigned short* __restrict__ Kh,   // (NH, M, 128)
    const unsigned short* __restrict__ Vt,   // (NH, B, 128, S)
    const unsigned int* __restrict__ mbits,  // (B, S, 16)
    unsigned short* __restrict__ ctx)        // (M, 512)
{
  const int lin = blockIdx.x;              // 0..1023
  const int work = (lin & 7) * 128 + (lin >> 3);
  const int qt = work & 3;
  const int h  = (work >> 2) & 3;
  const int b  = work >> 4;

  const int t = threadIdx.x;
  const int lane = t & 63;
  const int w = t >> 6;                    // 0..7
  const int quad = lane >> 4;
  const int l16 = lane & 15;

  __shared__ __align__(16) unsigned short Kld[64 * 136];   // 17408 B
  __shared__ __align__(16) unsigned short Vtld[128 * 72];  // 18432 B
  __shared__ __align__(16) unsigned short Pld[128 * 72];   // 18432 B

  const int q0 = qt * 128;
  const size_t rowbase = (size_t)b * SLEN;
  const unsigned short* kbase0 = Kh + ((size_t)h * MTOT + rowbase) * HID;
  const unsigned short* vbase  = Vt + (size_t)(h * BATCH + b) * HID * SLEN;
  const unsigned int* mrow = mbits + (size_t)b * SLEN * 16;

  const int k_key = t >> 4, k_col = (t & 15) << 3;   // +32 keys at i=1
  const int v_d   = t >> 3, v_cc  = (t & 7) << 3;    // +64 d at i=1

  short8 qa[4];
  {
    const unsigned short* qbase =
        Qh + ((size_t)h * MTOT + rowbase + q0 + w * 16 + l16) * HID + quad * 8;
    #pragma unroll
    for (int kk = 0; kk < 4; ++kk)
      qa[kk] = *(const short8*)(qbase + kk * 32);
  }

  short8 ones;
  #pragma unroll
  for (int j = 0; j < 8; ++j) ones[j] = (short)0x3F80;  // bf16 1.0

  f32x4 oc[8], oc9;
  #pragma unroll
  for (int nd = 0; nd < 8; ++nd) oc[nd] = f32x4{0.f, 0.f, 0.f, 0.f};
  oc9 = f32x4{0.f, 0.f, 0.f, 0.f};

  // prefetch chunk 0 into registers
  u32x4 kreg[2], vreg[2];
  #pragma unroll
  for (int i = 0; i < 2; ++i) {
    kreg[i] = *(const u32x4*)(kbase0 + (size_t)(k_key + i * 32) * HID + k_col);
    vreg[i] = *(const u32x4*)(vbase + (size_t)(v_d + i * 64) * SLEN + v_cc);
  }

  for (int c0 = 0; c0 < SLEN; c0 += 64) {
    if (c0) __syncthreads();   // prev chunk's LDS reads complete
    #pragma unroll
    for (int i = 0; i < 2; ++i) {
      *(u32x4*)(Kld + (k_key + i * 32) * 136 + k_col) = kreg[i];
      *(u32x4*)(Vtld + (v_d + i * 64) * 72 + v_cc) = vreg[i];
    }
    __syncthreads();
    if (c0 + 64 < SLEN) {
      #pragma unroll
      for (int i = 0; i < 2; ++i) {
        kreg[i] = *(const u32x4*)(kbase0 + (size_t)(c0 + 64 + k_key + i * 32) * HID + k_col);
        vreg[i] = *(const u32x4*)(vbase + (size_t)(v_d + i * 64) * SLEN + c0 + 64 + v_cc);
      }
    }

    // mask bits for this chunk
    u32x2 mw[4];
    #pragma unroll
    for (int r = 0; r < 4; ++r) {
      int qrow = q0 + w * 16 + quad * 4 + r;
      mw[r] = *(const u32x2*)(mrow + (size_t)qrow * 16 + (c0 >> 5));
    }

    // S = Q K^T (scale+log2e folded into Q)
    f32x4 sc[4];
    #pragma unroll
    for (int ni = 0; ni < 4; ++ni) sc[ni] = f32x4{0.f, 0.f, 0.f, 0.f};
    #pragma unroll
    for (int kk = 0; kk < 4; ++kk) {
      #pragma unroll
      for (int ni = 0; ni < 4; ++ni) {
        short8 bb = *(const short8*)(Kld + (ni * 16 + l16) * 136 + kk * 32 + quad * 8);
        sc[ni] = __builtin_amdgcn_mfma_f32_16x16x32_bf16(qa[kk], bb, sc[ni], 0, 0, 0);
      }
    }

    // p = mask ? exp2(s) : 0 ; write to Pld (wave-private rows -> fence only)
    #pragma unroll
    for (int ni = 0; ni < 4; ++ni) {
      int bit = (ni & 1) * 16 + l16;
      #pragma unroll
      for (int r = 0; r < 4; ++r) {
        unsigned wsel = (ni < 2) ? mw[r][0] : mw[r][1];
        float e = exp2f(sc[ni][r]);
        float p = ((wsel >> bit) & 1u) ? e : 0.f;
        Pld[(w * 16 + quad * 4 + r) * 72 + ni * 16 + l16] = f2bf(p);
      }
    }
    __threadfence_block();

    // O += P @ V ; rowsum += P @ 1
    #pragma unroll
    for (int kb = 0; kb < 2; ++kb) {
      short8 a = *(const short8*)(Pld + (w * 16 + l16) * 72 + kb * 32 + quad * 8);
      #pragma unroll
      for (int nd = 0; nd < 8; ++nd) {
        short8 bv = *(const short8*)(Vtld + (nd * 16 + l16) * 72 + kb * 32 + quad * 8);
        oc[nd] = __builtin_amdgcn_mfma_f32_16x16x32_bf16(a, bv, oc[nd], 0, 0, 0);
      }
      oc9 = __builtin_amdgcn_mfma_f32_16x16x32_bf16(a, ones, oc9, 0, 0, 0);
    }
  }

  // D[q][d] epilogue (write-combining scalar stores; R8's 8B scatter cost
  // +15 MB of partial-line write amplification)
  #pragma unroll
  for (int nd = 0; nd < 8; ++nd)
    #pragma unroll
    for (int r = 0; r < 4; ++r) {
      float val = oc[nd][r] / oc9[r];
      int row = q0 + w * 16 + quad * 4 + r;
      int col = h * HID + nd * 16 + l16;
      ctx[(rowbase + row) * DPROJ + col] = f2bf(val);
    }
}

// ---------------------------------------------------------------------------
// Kernel 3: fused output projection + residual + LayerNorm (R8 version).
// ---------------------------------------------------------------------------
__global__ __launch_bounds__(256, 4) void oproj_ln_kernel(
    const unsigned short* __restrict__ ctx,   // (M,512) bf16
    const unsigned short* __restrict__ WoT,   // (128,512) bf16 n-major
    const float* __restrict__ enc,            // (M,128) fp32
    const float* __restrict__ gamma,
    const float* __restrict__ beta,
    float* __restrict__ out)                  // (M,128) fp32
{
  const int m0 = blockIdx.x * 64;
  const int t = threadIdx.x;
  const int lane = t & 63;
  const int w = t >> 6;
  const int quad = lane >> 4;
  const int l16 = lane & 15;

  __shared__ __align__(16) unsigned short Actx[64 * 72];
  __shared__ __align__(16) unsigned short Bw[128 * 72];

  f32x4 acc[8];
  #pragma unroll
  for (int ni = 0; ni < 8; ++ni) acc[ni] = f32x4{0.f, 0.f, 0.f, 0.f};

  for (int kc = 0; kc < DPROJ; kc += 64) {
    __syncthreads();
    #pragma unroll
    for (int i = 0; i < 2; ++i) {
      int idx = i * 256 + t;
      int row = idx >> 3;
      int col = (idx & 7) << 3;
      *(u32x4*)(Actx + row * 72 + col) =
          *(const u32x4*)(ctx + (size_t)(m0 + row) * DPROJ + kc + col);
    }
    #pragma unroll
    for (int i = 0; i < 4; ++i) {
      int idx = i * 256 + t;
      int row = idx >> 3;
      int col = (idx & 7) << 3;
      *(u32x4*)(Bw + row * 72 + col) =
          *(const u32x4*)(WoT + (size_t)row * DPROJ + kc + col);
    }
    __syncthreads();
    #pragma unroll
    for (int kk = 0; kk < 2; ++kk) {
      short8 a = *(const short8*)(Actx + (w * 16 + l16) * 72 + kk * 32 + quad * 8);
      #pragma unroll
      for (int ni = 0; ni < 8; ++ni) {
        short8 bb = *(const short8*)(Bw + (ni * 16 + l16) * 72 + kk * 32 + quad * 8);
        acc[ni] = __builtin_amdgcn_mfma_f32_16x16x32_bf16(a, bb, acc[ni], 0, 0, 0);
      }
    }
  }

  float g[8], be[8];
  #pragma unroll
  for (int ni = 0; ni < 8; ++ni) {
    g[ni] = gamma[ni * 16 + l16];
    be[ni] = beta[ni * 16 + l16];
  }

  float val[8][4];
  #pragma unroll
  for (int r = 0; r < 4; ++r) {
    int m = m0 + w * 16 + quad * 4 + r;
    const float* erow = enc + (size_t)m * HID;
    float s = 0.f, s2 = 0.f;
    #pragma unroll
    for (int ni = 0; ni < 8; ++ni) {
      float v = acc[ni][r] + erow[ni * 16 + l16];
      val[ni][r] = v;
      s += v;
      s2 += v * v;
    }
    #pragma unroll
    for (int off = 1; off < 16; off <<= 1) {
      s  += __shfl_xor(s, off, 64);
      s2 += __shfl_xor(s2, off, 64);
    }
    float mean = s * (1.f / 128.f);
    float var = s2 * (1.f / 128.f) - mean * mean;
    float rstd = rsqrtf(var + 1e-6f);
    float* orow = out + (size_t)m * HID;
    #pragma unroll
    for (int ni = 0; ni < 8; ++ni)
      orow[ni * 16 + l16] = g[ni] * (val[ni][r] - mean) * rstd + be[ni];
  }
}

// ---------------------------------------------------------------------------
// ws layout (elements):
//   WT   : 3*512*128 shorts        WoT : 128*512 shorts
//   Qh   : 4*M*128 shorts          Kh  : 4*M*128 shorts
//   Vt   : 4*64*128*512 shorts     ctx : M*512 shorts
//   encb : M*128 shorts (fp32-sized slot)
//   mbits: 64*512*16 u32           (~153.6 MB total)
// ---------------------------------------------------------------------------
extern "C" void kernel_launch(void* const* d_in, const int* in_sizes, int n_in,
                              void* d_out, int out_size, void* d_ws, size_t ws_size,
                              hipStream_t stream) {
  const float* enc   = (const float*)d_in[0];
  const int*   mask  = (const int*)d_in[1];
  const float* Wq    = (const float*)d_in[2];
  const float* Wk    = (const float*)d_in[3];
  const float* Wv    = (const float*)d_in[4];
  const float* Wo    = (const float*)d_in[5];
  const float* gamma = (const float*)d_in[6];
  const float* beta  = (const float*)d_in[7];
  float* out = (float*)d_out;

  unsigned short* WT  = (unsigned short*)d_ws;
  unsigned short* WoT = WT + (size_t)3 * DPROJ * HID;
  unsigned short* Qh  = WoT + (size_t)HID * DPROJ;
  unsigned short* Kh  = Qh + (size_t)NHEAD * MTOT * HID;
  unsigned short* Vt  = Kh + (size_t)NHEAD * MTOT * HID;
  unsigned short* ctx = Vt + (size_t)NHEAD * MTOT * HID;
  unsigned short* encb = ctx + (size_t)MTOT * DPROJ;
  unsigned int* mbits = (unsigned int*)(encb + (size_t)MTOT * HID * 2);

  prep_kernel<<<19456, 256, 0, stream>>>(Wq, Wk, Wv, Wo, enc, mask, WT, WoT, encb, mbits);
  qkv_kernel<<<dim3(4, 256), 256, 0, stream>>>(encb, WT, Qh, Kh, Vt);
  attn_kernel<<<1024, 512, 0, stream>>>(Qh, Kh, Vt, mbits, ctx);
  oproj_ln_kernel<<<MTOT / 64, 256, 0, stream>>>(ctx, WoT, enc, gamma, beta, out);
}

// Round 11
// 233.415 us; speedup vs baseline: 1.7702x; 1.0385x over previous
//
#include <hip/hip_runtime.h>
#include <stdint.h>

#define BATCH 64
#define SLEN 512
#define HID 128
#define NHEAD 4
#define DPROJ 512            // HID * NHEAD
#define MTOT (BATCH * SLEN)  // 32768
#define SCALE 0.08838834764831845f
#define LOG2E 1.4426950408889634f

using short8 = __attribute__((ext_vector_type(8))) short;
using f32x4  = __attribute__((ext_vector_type(4))) float;
using u32x4  = __attribute__((ext_vector_type(4))) unsigned int;
using u32x2  = __attribute__((ext_vector_type(2))) unsigned int;
using us4    = __attribute__((ext_vector_type(4))) unsigned short;

__device__ __forceinline__ unsigned short f2bf(float f) {
  unsigned int u = __float_as_uint(f);
  u += 0x7fffu + ((u >> 16) & 1u);   // round-to-nearest-even
  return (unsigned short)(u >> 16);
}

// ---------------------------------------------------------------------------
// Kernel 0: prep. blocks 0..1023: weight cast+transpose (Wq pre-scaled by
// SCALE*log2(e) so attn uses exp2). blocks 1024..3071: enc fp32->bf16.
// blocks 3072..19455: mask -> bitmask.
// ---------------------------------------------------------------------------
__global__ __launch_bounds__(256) void prep_kernel(
    const float* __restrict__ Wq,
    const float* __restrict__ Wk,
    const float* __restrict__ Wv,
    const float* __restrict__ Wo,
    const float* __restrict__ enc,
    const int* __restrict__ mask,
    unsigned short* __restrict__ WT,
    unsigned short* __restrict__ WoT,
    unsigned short* __restrict__ encb,
    unsigned int* __restrict__ mbits)
{
  if (blockIdx.x < 1024) {
    int idx = blockIdx.x * 256 + threadIdx.x;
    int z = idx >> 16;
    int i = idx & 65535;
    if (z < 3) {
      const float* W = (z == 0) ? Wq : (z == 1) ? Wk : Wv;
      float scale = (z == 0) ? (SCALE * LOG2E) : 1.0f;  // exp2 form
      int k = i >> 9;
      int n = i & 511;
      WT[(size_t)z * 65536 + (size_t)n * 128 + k] = f2bf(W[i] * scale);
    } else {
      int k = i >> 7;
      int n = i & 127;
      WoT[(size_t)n * 512 + k] = f2bf(Wo[i]);
    }
  } else if (blockIdx.x < 3072) {
    size_t tid = (size_t)(blockIdx.x - 1024) * 256 + threadIdx.x;  // 0..524287
    const float* s = enc + tid * 8;
    f32x4 a0 = *(const f32x4*)(s);
    f32x4 a1 = *(const f32x4*)(s + 4);
    short8 v;
    #pragma unroll
    for (int j = 0; j < 4; ++j) v[j] = (short)f2bf(a0[j]);
    #pragma unroll
    for (int j = 0; j < 4; ++j) v[4 + j] = (short)f2bf(a1[j]);
    *(short8*)(encb + tid * 8) = v;
  } else {
    const int l = threadIdx.x & 63;
    size_t wavebase = (size_t)(blockIdx.x - 3072) * 1024 + (threadIdx.x >> 6) * 256;
    unsigned long long b0 = __ballot(mask[wavebase + 0 * 64 + l] != 0);
    unsigned long long b1 = __ballot(mask[wavebase + 1 * 64 + l] != 0);
    unsigned long long b2 = __ballot(mask[wavebase + 2 * 64 + l] != 0);
    unsigned long long b3 = __ballot(mask[wavebase + 3 * 64 + l] != 0);
    if (l < 4) {
      unsigned long long v = (l & 2) ? ((l & 1) ? b3 : b2) : ((l & 1) ? b1 : b0);
      *(unsigned long long*)(mbits + (wavebase >> 5) + l * 2) = v;
    }
  }
}

// ---------------------------------------------------------------------------
// Kernel 1: QKV projection. Grid (4 heads, 256 mt); z-loop inside; A staged
// once full-K (128x136), reused 3x. B restaged per 64-k half (128x72) ->
// LDS 53,248 B -> 3 blocks/CU (was 69,632 -> 2 blocks/CU).
// Q/K: swapped-operand MFMA (reg axis = d) -> packed us4 stores.
// V: written transposed (reg axis = s).
// ---------------------------------------------------------------------------
__global__ __launch_bounds__(256) void qkv_kernel(
    const unsigned short* __restrict__ encb,  // (M,128) bf16
    const unsigned short* __restrict__ WT,    // (3,512,128) bf16 n-major
    unsigned short* __restrict__ Qh,
    unsigned short* __restrict__ Kh,
    unsigned short* __restrict__ Vt)
{
  const int nt = blockIdx.x;   // 0..3 == head
  const int mt = blockIdx.y;   // 0..255
  const int t = threadIdx.x;
  const int lane = t & 63;
  const int w = t >> 6;
  const int quad = lane >> 4;
  const int l16 = lane & 15;

  __shared__ __align__(16) unsigned short Ald[128 * 136];  // 34816 B
  __shared__ __align__(16) unsigned short Bld[128 * 72];   // 18432 B

  const int m0 = mt * 128, n0 = nt * 128;
  const int wm = (w >> 1) * 64, wn = (w & 1) * 64;

  // stage A once: 128x128 shorts = 2048 vec8, 8 per thread
  #pragma unroll
  for (int i = 0; i < 8; ++i) {
    int idx = i * 256 + t;
    int row = idx >> 4;
    int col = (idx & 15) << 3;
    *(u32x4*)(Ald + row * 136 + col) =
        *(const u32x4*)(encb + (size_t)(m0 + row) * HID + col);
  }

  for (int z = 0; z < 3; ++z) {
    const unsigned short* Wz = WT + (size_t)z * DPROJ * HID;

    f32x4 acc[4][4];
    #pragma unroll
    for (int mi = 0; mi < 4; ++mi)
      #pragma unroll
      for (int ni = 0; ni < 4; ++ni)
        acc[mi][ni] = f32x4{0.f, 0.f, 0.f, 0.f};

    #pragma unroll
    for (int kc = 0; kc < 2; ++kc) {
      __syncthreads();   // also covers A visibility (z==0,kc==0) and Bld reuse
      // stage B half: 128 rows x 64 k = 1024 vec8, 4 per thread
      #pragma unroll
      for (int i = 0; i < 4; ++i) {
        int idx = i * 256 + t;
        int row = idx >> 3;
        int col = (idx & 7) << 3;
        *(u32x4*)(Bld + row * 72 + col) =
            *(const u32x4*)(Wz + (size_t)(n0 + row) * HID + kc * 64 + col);
      }
      __syncthreads();

      #pragma unroll
      for (int kk = 0; kk < 2; ++kk) {
        short8 a[4], bb[4];
        #pragma unroll
        for (int mi = 0; mi < 4; ++mi)
          a[mi] = *(const short8*)(Ald + (wm + mi * 16 + l16) * 136 + kc * 64 + kk * 32 + quad * 8);
        #pragma unroll
        for (int ni = 0; ni < 4; ++ni)
          bb[ni] = *(const short8*)(Bld + (wn + ni * 16 + l16) * 72 + kk * 32 + quad * 8);
        if (z < 2) {
          #pragma unroll
          for (int mi = 0; mi < 4; ++mi)
            #pragma unroll
            for (int ni = 0; ni < 4; ++ni)
              acc[mi][ni] = __builtin_amdgcn_mfma_f32_16x16x32_bf16(bb[ni], a[mi], acc[mi][ni], 0, 0, 0);
        } else {
          #pragma unroll
          for (int mi = 0; mi < 4; ++mi)
            #pragma unroll
            for (int ni = 0; ni < 4; ++ni)
              acc[mi][ni] = __builtin_amdgcn_mfma_f32_16x16x32_bf16(a[mi], bb[ni], acc[mi][ni], 0, 0, 0);
        }
      }
    }

    if (z < 2) {
      // D[n][m]: col(l16)=m-within-16, row(quad*4+r)=d-within-16
      unsigned short* outz = ((z == 0) ? Qh : Kh) + (size_t)nt * MTOT * HID;
      #pragma unroll
      for (int mi = 0; mi < 4; ++mi)
        #pragma unroll
        for (int ni = 0; ni < 4; ++ni) {
          int m = m0 + wm + mi * 16 + l16;
          int dbase = wn + ni * 16 + quad * 4;
          us4 pk;
          #pragma unroll
          for (int r = 0; r < 4; ++r) pk[r] = f2bf(acc[mi][ni][r]);
          *(us4*)(outz + (size_t)m * HID + dbase) = pk;
        }
    } else {
      // D[m][n]: reg axis = s (4 consecutive) -> Vt[(nt*B+b)*128 + d][s]
      #pragma unroll
      for (int mi = 0; mi < 4; ++mi)
        #pragma unroll
        for (int ni = 0; ni < 4; ++ni) {
          int row0 = m0 + wm + mi * 16 + quad * 4;
          int b = row0 >> 9, s = row0 & 511;
          int d = wn + ni * 16 + l16;
          us4 pk;
          #pragma unroll
          for (int r = 0; r < 4; ++r) pk[r] = f2bf(acc[mi][ni][r]);
          *(us4*)(Vt + ((size_t)(nt * BATCH + b) * HID + d) * SLEN + s) = pk;
        }
    }
  }
}

// ---------------------------------------------------------------------------
// Kernel 2: flash attention — R6 structure (measured best). 128-q tile,
// 512 thr, XCD swizzle, K/V register prefetch into LDS. Pld padded + fence.
// Changes vs R10: raw __builtin_amdgcn_exp2f (libm exp2f's precise-mode
// wrapper cost ~8 pts VALUBusy, R10), rcp epilogue instead of 32 fp32 divs.
// launch_bounds (512,4): (512,6) caps VGPR at 85 -> spills (R7).
// ---------------------------------------------------------------------------
__global__ __launch_bounds__(512, 4) void attn_kernel(
    const unsigned short* __restrict__ Qh,   // (NH, M, 128)
    const unsigned short* __restrict__ Kh,   // (NH, M, 128)
    const unsigned short* __restrict__ Vt,   // (NH, B, 128, S)
    const unsigned int* __restrict__ mbits,  // (B, S, 16)
    unsigned short* __restrict__ ctx)        // (M, 512)
{
  const int lin = blockIdx.x;              // 0..1023
  const int work = (lin & 7) * 128 + (lin >> 3);
  const int qt = work & 3;
  const int h  = (work >> 2) & 3;
  const int b  = work >> 4;

  const int t = threadIdx.x;
  const int lane = t & 63;
  const int w = t >> 6;                    // 0..7
  const int quad = lane >> 4;
  const int l16 = lane & 15;

  __shared__ __align__(16) unsigned short Kld[64 * 136];   // 17408 B
  __shared__ __align__(16) unsigned short Vtld[128 * 72];  // 18432 B
  __shared__ __align__(16) unsigned short Pld[128 * 72];   // 18432 B

  const int q0 = qt * 128;
  const size_t rowbase = (size_t)b * SLEN;
  const unsigned short* kbase0 = Kh + ((size_t)h * MTOT + rowbase) * HID;
  const unsigned short* vbase  = Vt + (size_t)(h * BATCH + b) * HID * SLEN;
  const unsigned int* mrow = mbits + (size_t)b * SLEN * 16;

  const int k_key = t >> 4, k_col = (t & 15) << 3;   // +32 keys at i=1
  const int v_d   = t >> 3, v_cc  = (t & 7) << 3;    // +64 d at i=1

  short8 qa[4];
  {
    const unsigned short* qbase =
        Qh + ((size_t)h * MTOT + rowbase + q0 + w * 16 + l16) * HID + quad * 8;
    #pragma unroll
    for (int kk = 0; kk < 4; ++kk)
      qa[kk] = *(const short8*)(qbase + kk * 32);
  }

  short8 ones;
  #pragma unroll
  for (int j = 0; j < 8; ++j) ones[j] = (short)0x3F80;  // bf16 1.0

  f32x4 oc[8], oc9;
  #pragma unroll
  for (int nd = 0; nd < 8; ++nd) oc[nd] = f32x4{0.f, 0.f, 0.f, 0.f};
  oc9 = f32x4{0.f, 0.f, 0.f, 0.f};

  // prefetch chunk 0 into registers
  u32x4 kreg[2], vreg[2];
  #pragma unroll
  for (int i = 0; i < 2; ++i) {
    kreg[i] = *(const u32x4*)(kbase0 + (size_t)(k_key + i * 32) * HID + k_col);
    vreg[i] = *(const u32x4*)(vbase + (size_t)(v_d + i * 64) * SLEN + v_cc);
  }

  for (int c0 = 0; c0 < SLEN; c0 += 64) {
    if (c0) __syncthreads();   // prev chunk's LDS reads complete
    #pragma unroll
    for (int i = 0; i < 2; ++i) {
      *(u32x4*)(Kld + (k_key + i * 32) * 136 + k_col) = kreg[i];
      *(u32x4*)(Vtld + (v_d + i * 64) * 72 + v_cc) = vreg[i];
    }
    __syncthreads();
    if (c0 + 64 < SLEN) {
      #pragma unroll
      for (int i = 0; i < 2; ++i) {
        kreg[i] = *(const u32x4*)(kbase0 + (size_t)(c0 + 64 + k_key + i * 32) * HID + k_col);
        vreg[i] = *(const u32x4*)(vbase + (size_t)(v_d + i * 64) * SLEN + c0 + 64 + v_cc);
      }
    }

    // mask bits for this chunk
    u32x2 mw[4];
    #pragma unroll
    for (int r = 0; r < 4; ++r) {
      int qrow = q0 + w * 16 + quad * 4 + r;
      mw[r] = *(const u32x2*)(mrow + (size_t)qrow * 16 + (c0 >> 5));
    }

    // S = Q K^T (scale+log2e folded into Q)
    f32x4 sc[4];
    #pragma unroll
    for (int ni = 0; ni < 4; ++ni) sc[ni] = f32x4{0.f, 0.f, 0.f, 0.f};
    #pragma unroll
    for (int kk = 0; kk < 4; ++kk) {
      #pragma unroll
      for (int ni = 0; ni < 4; ++ni) {
        short8 bb = *(const short8*)(Kld + (ni * 16 + l16) * 136 + kk * 32 + quad * 8);
        sc[ni] = __builtin_amdgcn_mfma_f32_16x16x32_bf16(qa[kk], bb, sc[ni], 0, 0, 0);
      }
    }

    // p = mask ? exp2(s) : 0 ; write to Pld (wave-private rows -> fence only)
    #pragma unroll
    for (int ni = 0; ni < 4; ++ni) {
      int bit = (ni & 1) * 16 + l16;
      #pragma unroll
      for (int r = 0; r < 4; ++r) {
        unsigned wsel = (ni < 2) ? mw[r][0] : mw[r][1];
        float e = __builtin_amdgcn_exp2f(sc[ni][r]);   // raw v_exp_f32
        float p = ((wsel >> bit) & 1u) ? e : 0.f;
        Pld[(w * 16 + quad * 4 + r) * 72 + ni * 16 + l16] = f2bf(p);
      }
    }
    __threadfence_block();

    // O += P @ V ; rowsum += P @ 1
    #pragma unroll
    for (int kb = 0; kb < 2; ++kb) {
      short8 a = *(const short8*)(Pld + (w * 16 + l16) * 72 + kb * 32 + quad * 8);
      #pragma unroll
      for (int nd = 0; nd < 8; ++nd) {
        short8 bv = *(const short8*)(Vtld + (nd * 16 + l16) * 72 + kb * 32 + quad * 8);
        oc[nd] = __builtin_amdgcn_mfma_f32_16x16x32_bf16(a, bv, oc[nd], 0, 0, 0);
      }
      oc9 = __builtin_amdgcn_mfma_f32_16x16x32_bf16(a, ones, oc9, 0, 0, 0);
    }
  }

  // D[q][d] epilogue: rcp once per row, multiply (was 32 fp32 divides)
  float rcp[4];
  #pragma unroll
  for (int r = 0; r < 4; ++r) rcp[r] = __builtin_amdgcn_rcpf(oc9[r]);
  #pragma unroll
  for (int nd = 0; nd < 8; ++nd)
    #pragma unroll
    for (int r = 0; r < 4; ++r) {
      float val = oc[nd][r] * rcp[r];
      int row = q0 + w * 16 + quad * 4 + r;
      int col = h * HID + nd * 16 + l16;
      ctx[(rowbase + row) * DPROJ + col] = f2bf(val);
    }
}

// ---------------------------------------------------------------------------
// Kernel 3: fused output projection + residual + LayerNorm (R8 version).
// ---------------------------------------------------------------------------
__global__ __launch_bounds__(256, 4) void oproj_ln_kernel(
    const unsigned short* __restrict__ ctx,   // (M,512) bf16
    const unsigned short* __restrict__ WoT,   // (128,512) bf16 n-major
    const float* __restrict__ enc,            // (M,128) fp32
    const float* __restrict__ gamma,
    const float* __restrict__ beta,
    float* __restrict__ out)                  // (M,128) fp32
{
  const int m0 = blockIdx.x * 64;
  const int t = threadIdx.x;
  const int lane = t & 63;
  const int w = t >> 6;
  const int quad = lane >> 4;
  const int l16 = lane & 15;

  __shared__ __align__(16) unsigned short Actx[64 * 72];
  __shared__ __align__(16) unsigned short Bw[128 * 72];

  f32x4 acc[8];
  #pragma unroll
  for (int ni = 0; ni < 8; ++ni) acc[ni] = f32x4{0.f, 0.f, 0.f, 0.f};

  for (int kc = 0; kc < DPROJ; kc += 64) {
    __syncthreads();
    #pragma unroll
    for (int i = 0; i < 2; ++i) {
      int idx = i * 256 + t;
      int row = idx >> 3;
      int col = (idx & 7) << 3;
      *(u32x4*)(Actx + row * 72 + col) =
          *(const u32x4*)(ctx + (size_t)(m0 + row) * DPROJ + kc + col);
    }
    #pragma unroll
    for (int i = 0; i < 4; ++i) {
      int idx = i * 256 + t;
      int row = idx >> 3;
      int col = (idx & 7) << 3;
      *(u32x4*)(Bw + row * 72 + col) =
          *(const u32x4*)(WoT + (size_t)row * DPROJ + kc + col);
    }
    __syncthreads();
    #pragma unroll
    for (int kk = 0; kk < 2; ++kk) {
      short8 a = *(const short8*)(Actx + (w * 16 + l16) * 72 + kk * 32 + quad * 8);
      #pragma unroll
      for (int ni = 0; ni < 8; ++ni) {
        short8 bb = *(const short8*)(Bw + (ni * 16 + l16) * 72 + kk * 32 + quad * 8);
        acc[ni] = __builtin_amdgcn_mfma_f32_16x16x32_bf16(a, bb, acc[ni], 0, 0, 0);
      }
    }
  }

  float g[8], be[8];
  #pragma unroll
  for (int ni = 0; ni < 8; ++ni) {
    g[ni] = gamma[ni * 16 + l16];
    be[ni] = beta[ni * 16 + l16];
  }

  float val[8][4];
  #pragma unroll
  for (int r = 0; r < 4; ++r) {
    int m = m0 + w * 16 + quad * 4 + r;
    const float* erow = enc + (size_t)m * HID;
    float s = 0.f, s2 = 0.f;
    #pragma unroll
    for (int ni = 0; ni < 8; ++ni) {
      float v = acc[ni][r] + erow[ni * 16 + l16];
      val[ni][r] = v;
      s += v;
      s2 += v * v;
    }
    #pragma unroll
    for (int off = 1; off < 16; off <<= 1) {
      s  += __shfl_xor(s, off, 64);
      s2 += __shfl_xor(s2, off, 64);
    }
    float mean = s * (1.f / 128.f);
    float var = s2 * (1.f / 128.f) - mean * mean;
    float rstd = rsqrtf(var + 1e-6f);
    float* orow = out + (size_t)m * HID;
    #pragma unroll
    for (int ni = 0; ni < 8; ++ni)
      orow[ni * 16 + l16] = g[ni] * (val[ni][r] - mean) * rstd + be[ni];
  }
}

// ---------------------------------------------------------------------------
// ws layout (elements):
//   WT   : 3*512*128 shorts        WoT : 128*512 shorts
//   Qh   : 4*M*128 shorts          Kh  : 4*M*128 shorts
//   Vt   : 4*64*128*512 shorts     ctx : M*512 shorts
//   encb : M*128 shorts (fp32-sized slot)
//   mbits: 64*512*16 u32           (~153.6 MB total)
// ---------------------------------------------------------------------------
extern "C" void kernel_launch(void* const* d_in, const int* in_sizes, int n_in,
                              void* d_out, int out_size, void* d_ws, size_t ws_size,
                              hipStream_t stream) {
  const float* enc   = (const float*)d_in[0];
  const int*   mask  = (const int*)d_in[1];
  const float* Wq    = (const float*)d_in[2];
  const float* Wk    = (const float*)d_in[3];
  const float* Wv    = (const float*)d_in[4];
  const float* Wo    = (const float*)d_in[5];
  const float* gamma = (const float*)d_in[6];
  const float* beta  = (const float*)d_in[7];
  float* out = (float*)d_out;

  unsigned short* WT  = (unsigned short*)d_ws;
  unsigned short* WoT = WT + (size_t)3 * DPROJ * HID;
  unsigned short* Qh  = WoT + (size_t)HID * DPROJ;
  unsigned short* Kh  = Qh + (size_t)NHEAD * MTOT * HID;
  unsigned short* Vt  = Kh + (size_t)NHEAD * MTOT * HID;
  unsigned short* ctx = Vt + (size_t)NHEAD * MTOT * HID;
  unsigned short* encb = ctx + (size_t)MTOT * DPROJ;
  unsigned int* mbits = (unsigned int*)(encb + (size_t)MTOT * HID * 2);

  prep_kernel<<<19456, 256, 0, stream>>>(Wq, Wk, Wv, Wo, enc, mask, WT, WoT, encb, mbits);
  qkv_kernel<<<dim3(4, 256), 256, 0, stream>>>(encb, WT, Qh, Kh, Vt);
  attn_kernel<<<1024, 512, 0, stream>>>(Qh, Kh, Vt, mbits, ctx);
  oproj_ln_kernel<<<MTOT / 64, 256, 0, stream>>>(ctx, WoT, enc, gamma, beta, out);
}